// Round 4
// baseline (663163.379 us; speedup 1.0000x reference)
//
#include <hip/hip_runtime.h>
#include <math.h>

// ============================================================
// Tacotron2 decoder, fp32. Round 5: persistent decode, L3-resident streams.
// B=64, T_ENC=512, T_DEC=500, MEL=80, PRE=256, ENC_D=512, H=1024, ATT=128
//
// Round-4 finding: nontemporal hints prevented Infinity-Cache (L3) residency
// -> 139 MB/step refetched from HBM at 652 GB/s = the entire step time.
// Round-5: plain (cached) loads everywhere -> 147 MB working set lives in
// 256 MB L3; depth-2 weight prefetch (even/odd reg sets) hides L3 latency.
// ============================================================

// ---------------- ws layout (float offsets) ----------------
static constexpr long OFF_AMT  = 0;                       // amT[512][128]
static constexpr long OFF_P1WT = OFF_AMT  + 512L*128;     // p1wT[80][256]
static constexpr long OFF_P2WT = OFF_P1WT + 80L*256;      // p2wT[256][256]
static constexpr long OFF_MWT  = OFF_P2WT + 256L*256;     // mwT (unused by decode)
static constexpr long OFF_AQT  = OFF_MWT  + 1536L*80;     // aqT (unused by decode)
static constexpr long OFF_WLOC = OFF_AQT  + 1024L*128;    // W_loc[128][32] (legacy)
static constexpr long OFF_BLOC = OFF_WLOC + 128L*32;      // bloc[128] = al@alcb + ab
static constexpr long OFF_WLT  = OFF_BLOC + 128;          // WlT[32][128]
static constexpr long OFF_GB0  = OFF_WLT  + 4096;         // bih0+bhh0 [4096]
static constexpr long OFF_GB1  = OFF_GB0  + 4096;         // bih1+bhh1 [4096]
static constexpr long OFF_PWT0 = OFF_GB1  + 4096;         // postnet wT0 [400][512]
static constexpr long OFF_PWT1 = OFF_PWT0 + 400L*512;     // [2560][512]
static constexpr long OFF_PWT2 = OFF_PWT1 + 2560L*512;
static constexpr long OFF_PWT3 = OFF_PWT2 + 2560L*512;
static constexpr long OFF_PWT4 = OFF_PWT3 + 2560L*512;    // [2560][80]
static constexpr long OFF_PRE  = OFF_PWT4 + 2560L*80;     // pre_all[500*64][256]
static constexpr long OFF_MEM  = OFF_PRE  + 500L*64*256;  // mem[64][512][128]
static constexpr long OFF_H0A  = OFF_MEM  + 64L*512*128;  // -- zero region start --
static constexpr long OFF_H0B  = OFF_H0A  + 64L*1024;
static constexpr long OFF_H1A  = OFF_H0B  + 64L*1024;
static constexpr long OFF_H1B  = OFF_H1A  + 64L*1024;
static constexpr long OFF_C0   = OFF_H1B  + 64L*1024;
static constexpr long OFF_C1   = OFF_C0   + 64L*1024;
static constexpr long OFF_Q    = OFF_C1   + 64L*1024;     // q[64][128]
static constexpr long OFF_CTX  = OFF_Q    + 64L*128;      // ctx[64][512]
static constexpr long OFF_EBUF = OFF_CTX  + 64L*512;      // e[64][512]
static constexpr long OFF_PB0  = OFF_EBUF + 64L*512;      // postnet buf [64][512][500]
static constexpr long OFF_PB1  = OFF_PB0  + 64L*512*500;
static constexpr long WS_FLOATS = OFF_PB1 + 64L*512*500;  // ~201.5 MB

static constexpr long OFF_BAR = OFF_PB0;   // barrier flags (re-init by k_prep)

// d_out layout: [mel+post | mel | stop | attw]
static constexpr long DO_MEL  = 64L*500*80;
static constexpr long DO_STOP = 2*DO_MEL;
static constexpr long DO_ATT  = DO_STOP + 64L*500;

static constexpr long ZERO_CNT = OFF_EBUF - OFF_H0A;
static constexpr long PREP_TOTAL = ZERO_CNT + 4096 + 4096 + 4096 + 128 + 4096
  + 65536 + 20480 + 65536 + 122880 + 131072
  + 204800 + 1310720 + 1310720 + 1310720 + 204800;

static constexpr int NBLK = 256;
static constexpr int NTHR = 512;

typedef float f4 __attribute__((ext_vector_type(4)));

__device__ __forceinline__ float fsigmoid(float x) { return 1.f / (1.f + __expf(-x)); }
__device__ __forceinline__ float ftanh(float x) {
  float ax = fminf(fabsf(x), 15.f);
  float e = __expf(-2.f * ax);
  float r = (1.f - e) / (1.f + e);
  return copysignf(r, x);
}
__device__ __forceinline__ float4 ld4(const float* p) { return *(const float4*)p; }
__device__ __forceinline__ f4 ld4v(const float* p) { return *(const f4*)p; }
__device__ __forceinline__ float dot4(float4 w, float4 x, float acc) {
  acc = fmaf(w.x, x.x, acc); acc = fmaf(w.y, x.y, acc);
  acc = fmaf(w.z, x.z, acc); acc = fmaf(w.w, x.w, acc);
  return acc;
}
__device__ __forceinline__ float dot4v(f4 w, float4 x, float acc) {
  acc = fmaf(w.x, x.x, acc); acc = fmaf(w.y, x.y, acc);
  acc = fmaf(w.z, x.z, acc); acc = fmaf(w.w, x.w, acc);
  return acc;
}

// ---------------- parallel flag-tree grid barrier ----------------
__device__ __forceinline__ void gbar(unsigned* bar, unsigned gen) {
  __syncthreads();
  if (blockIdx.x == 0) {
    if (threadIdx.x > 0 && threadIdx.x < 256) {
      while (__hip_atomic_load(&bar[threadIdx.x*16], __ATOMIC_RELAXED,
                               __HIP_MEMORY_SCOPE_AGENT) != gen)
        __builtin_amdgcn_s_sleep(1);
    }
    __syncthreads();
    if (threadIdx.x == 0)
      __hip_atomic_store(&bar[4096], gen, __ATOMIC_RELEASE, __HIP_MEMORY_SCOPE_AGENT);
  } else {
    if (threadIdx.x == 0) {
      __hip_atomic_store(&bar[blockIdx.x*16], gen, __ATOMIC_RELEASE,
                         __HIP_MEMORY_SCOPE_AGENT);
      while (__hip_atomic_load(&bar[4096], __ATOMIC_RELAXED,
                               __HIP_MEMORY_SCOPE_AGENT) != gen)
        __builtin_amdgcn_s_sleep(1);
    }
  }
  if (threadIdx.x == 0) __threadfence();
  __syncthreads();
}

// ---------------- prolog: transposes / fused constants / zero-init ----------------
__global__ __launch_bounds__(256) void k_prep(
    const float* __restrict__ bih0, const float* __restrict__ bhh0,
    const float* __restrict__ bih1, const float* __restrict__ bhh1,
    const float* __restrict__ al,   const float* __restrict__ alcw,
    const float* __restrict__ alcb, const float* __restrict__ ab,
    const float* __restrict__ am,   const float* __restrict__ p1w,
    const float* __restrict__ p2w,  const float* __restrict__ mw,
    const float* __restrict__ aq,
    const float* __restrict__ pw0, const float* __restrict__ pw1,
    const float* __restrict__ pw2, const float* __restrict__ pw3,
    const float* __restrict__ pw4,
    float* __restrict__ ws)
{
  if (blockIdx.x == 0) {
    unsigned* bar = (unsigned*)(ws + OFF_BAR);
    for (int i = threadIdx.x; i < 4160; i += 256) bar[i] = 0u;
  }
  long stride = (long)gridDim.x * 256;
  for (long idx = (long)blockIdx.x * 256 + threadIdx.x; idx < PREP_TOTAL; idx += stride) {
    long r = idx;
    if (r < ZERO_CNT) { ws[OFF_H0A + r] = 0.f; continue; }
    r -= ZERO_CNT;
    if (r < 4096) { ws[OFF_GB0 + r] = bih0[r] + bhh0[r]; continue; }
    r -= 4096;
    if (r < 4096) { ws[OFF_GB1 + r] = bih1[r] + bhh1[r]; continue; }
    r -= 4096;
    if (r < 4096) {
      int a = (int)(r >> 5), k = (int)(r & 31);
      float v = 0.f;
      if (k < 31) for (int ch = 0; ch < 32; ++ch) v += al[a*32 + ch] * alcw[ch*31 + k];
      ws[OFF_WLOC + r] = v; continue;
    }
    r -= 4096;
    if (r < 128) {
      float v = ab[r];
      for (int ch = 0; ch < 32; ++ch) v += al[r*32 + ch] * alcb[ch];
      ws[OFF_BLOC + r] = v; continue;
    }
    r -= 128;
    if (r < 4096) {   // WlT[k][a]
      int k = (int)(r >> 7), a = (int)(r & 127);
      float v = 0.f;
      if (k < 31) for (int ch = 0; ch < 32; ++ch) v += al[a*32 + ch] * alcw[ch*31 + k];
      ws[OFF_WLT + r] = v; continue;
    }
    r -= 4096;
    if (r < 65536) { int d = (int)(r >> 7), a2 = (int)(r & 127); ws[OFF_AMT + r] = am[(long)a2*512 + d]; continue; }
    r -= 65536;
    if (r < 20480) { int k = (int)(r >> 8), j = (int)(r & 255); ws[OFF_P1WT + r] = p1w[j*80 + k]; continue; }
    r -= 20480;
    if (r < 65536) { int k = (int)(r >> 8), j = (int)(r & 255); ws[OFF_P2WT + r] = p2w[j*256 + k]; continue; }
    r -= 65536;
    if (r < 122880) { int k = (int)(r / 80), c = (int)(r % 80); ws[OFF_MWT + r] = mw[(long)c*1536 + k]; continue; }
    r -= 122880;
    if (r < 131072) { int k = (int)(r >> 7), a2 = (int)(r & 127); ws[OFF_AQT + r] = aq[(long)a2*1024 + k]; continue; }
    r -= 131072;
    if (r < 204800) { int c5 = (int)(r / 512), co = (int)(r % 512); ws[OFF_PWT0 + r] = pw0[((long)co*80  + c5/5)*5 + (c5%5)]; continue; }
    r -= 204800;
    if (r < 1310720) { int c5 = (int)(r / 512), co = (int)(r % 512); ws[OFF_PWT1 + r] = pw1[((long)co*512 + c5/5)*5 + (c5%5)]; continue; }
    r -= 1310720;
    if (r < 1310720) { int c5 = (int)(r / 512), co = (int)(r % 512); ws[OFF_PWT2 + r] = pw2[((long)co*512 + c5/5)*5 + (c5%5)]; continue; }
    r -= 1310720;
    if (r < 1310720) { int c5 = (int)(r / 512), co = (int)(r % 512); ws[OFF_PWT3 + r] = pw3[((long)co*512 + c5/5)*5 + (c5%5)]; continue; }
    r -= 1310720;
    { int c5 = (int)(r / 80), co = (int)(r % 80); ws[OFF_PWT4 + r] = pw4[((long)co*512 + c5/5)*5 + (c5%5)]; }
  }
}

// ---------------- prolog: prenet for all 500 steps ----------------
__global__ __launch_bounds__(256) void k_prenet(
    const float* __restrict__ mel_tgt, const float* __restrict__ p1b,
    const float* __restrict__ p2b, float* __restrict__ ws)
{
  int t = blockIdx.x, tid = threadIdx.x;
  const float* p1wT = ws + OFF_P1WT;
  const float* p2wT = ws + OFF_P2WT;
  __shared__ float prev_s[16][80];
  __shared__ float h1_s[16][256];
  for (int sb = 0; sb < 4; ++sb) {
    int b0 = sb * 16;
    for (int i = tid; i < 16*80; i += 256) {
      int rr = i / 80, k = i - rr*80;
      float v = 0.f;
      if (t > 0) v = mel_tgt[((long)(b0 + rr)*500 + (t-1))*80 + k];
      prev_s[rr][k] = v;
    }
    __syncthreads();
    int j = tid;
    for (int rr = 0; rr < 16; ++rr) {
      float acc = p1b[j];
      for (int k = 0; k < 80; ++k) acc = fmaf(prev_s[rr][k], p1wT[k*256 + j], acc);
      h1_s[rr][j] = fmaxf(acc, 0.f);
    }
    __syncthreads();
    for (int rr = 0; rr < 16; ++rr) {
      float acc = p2b[j];
      for (int k = 0; k < 256; ++k) acc = fmaf(h1_s[rr][k], p2wT[k*256 + j], acc);
      ws[OFF_PRE + ((long)t*64 + b0 + rr)*256 + j] = fmaxf(acc, 0.f);
    }
    __syncthreads();
  }
}

// ---------------- prolog: mem = enc @ am.T ----------------
__global__ __launch_bounds__(256) void k_mem(const float* __restrict__ enc, float* __restrict__ ws)
{
  int row0 = blockIdx.x * 16;
  int tid = threadIdx.x;
  int a = tid & 127, rh = tid >> 7;
  const float* amT = ws + OFF_AMT;
  __shared__ float encS[16][65];
  float acc[8];
#pragma unroll
  for (int i = 0; i < 8; ++i) acc[i] = 0.f;
  for (int k0 = 0; k0 < 512; k0 += 64) {
    for (int i = tid; i < 16*64; i += 256) {
      int rr = i >> 6, kk = i & 63;
      encS[rr][kk] = enc[(long)(row0 + rr)*512 + k0 + kk];
    }
    __syncthreads();
    for (int kk = 0; kk < 64; ++kk) {
      float w = amT[(long)(k0 + kk)*128 + a];
#pragma unroll
      for (int rr = 0; rr < 8; ++rr) acc[rr] = fmaf(encS[rh*8 + rr][kk], w, acc[rr]);
    }
    __syncthreads();
  }
#pragma unroll
  for (int rr = 0; rr < 8; ++rr)
    ws[OFF_MEM + (long)(row0 + rh*8 + rr)*128 + a] = acc[rr];
}

// ---------------- persistent fused decode kernel ----------------
struct SmemE { float ap[160]; float bq[128]; float ep[4][132]; };
struct SmemS { float es[512]; float wred[8]; float wsum[8]; float red[16][132]; };
struct SmemG { float xw[8][8][64]; float gsh[16][65]; };   // per-wave x buffers
struct SmemM { float xs[1536]; };
union SmemU { SmemE e; SmemS s; SmemG g; SmemM m; };

__global__ __launch_bounds__(NTHR) void k_decode(
    const float* __restrict__ enc, const float* __restrict__ ae,
    const float* __restrict__ wih0, const float* __restrict__ whh0,
    const float* __restrict__ wih1, const float* __restrict__ whh1,
    const float* __restrict__ mw, const float* __restrict__ mb,
    const float* __restrict__ sw, const float* __restrict__ sb,
    const float* __restrict__ aq,
    float* __restrict__ dout, float* __restrict__ ws)
{
  const int B = blockIdx.x;
  const int tid = threadIdx.x;
  unsigned* bar = (unsigned*)(ws + OFF_BAR);
  unsigned gen = 0;

  __shared__ float WlTs[4096];
  __shared__ float aeS[128];
  __shared__ SmemU U;

  for (int i = tid; i < 4096; i += NTHR) WlTs[i] = ws[OFF_WLT + i];
  if (tid < 128) aeS[tid] = ae[tid];
  __syncthreads();

  for (int t = 0; t < 500; ++t) {
    const int p = t & 1;

    // ========== phase E: attention energies (block = b x te-chunk128) ==========
    {
      const int b = B & 63, cc2 = B >> 6;
      const int te0 = cc2 * 128;
      const int tel = tid & 127, ag = tid >> 7;
      const int a0 = ag * 32;
      for (int i = tid; i < 158; i += NTHR) {
        int gte = te0 + i - 15;
        float v = 0.f;
        if (t > 0 && gte >= 0 && gte < 512)
          v = dout[DO_ATT + ((long)b*500 + (t-1))*512 + gte];
        U.e.ap[i] = v;
      }
      if (tid < 128) U.e.bq[tid] = ws[OFF_Q + b*128 + tid] + ws[OFF_BLOC + tid];
      __syncthreads();
      float acc[32];
#pragma unroll
      for (int i = 0; i < 32; ++i) acc[i] = 0.f;
      for (int k = 0; k < 31; ++k) {
        float apk = U.e.ap[tel + k];
#pragma unroll
        for (int a4 = 0; a4 < 8; ++a4) {
          float4 wv = ld4(&WlTs[k*128 + a0 + a4*4]);
          acc[a4*4+0] = fmaf(apk, wv.x, acc[a4*4+0]);
          acc[a4*4+1] = fmaf(apk, wv.y, acc[a4*4+1]);
          acc[a4*4+2] = fmaf(apk, wv.z, acc[a4*4+2]);
          acc[a4*4+3] = fmaf(apk, wv.w, acc[a4*4+3]);
        }
      }
      const float* memp = ws + OFF_MEM + ((long)b*512 + te0 + tel)*128 + a0;
      float esum = 0.f;
#pragma unroll
      for (int a4 = 0; a4 < 8; ++a4) {
        f4 mv = ld4v(&memp[a4*4]);      // cached: mem is L3-resident
        float4 bq = ld4(&U.e.bq[a0 + a4*4]);
        float4 av = ld4(&aeS[a0 + a4*4]);
        esum = fmaf(av.x, ftanh(acc[a4*4+0] + bq.x + mv.x), esum);
        esum = fmaf(av.y, ftanh(acc[a4*4+1] + bq.y + mv.y), esum);
        esum = fmaf(av.z, ftanh(acc[a4*4+2] + bq.z + mv.z), esum);
        esum = fmaf(av.w, ftanh(acc[a4*4+3] + bq.w + mv.w), esum);
      }
      U.e.ep[ag][tel] = esum;
      __syncthreads();
      if (tid < 128)
        ws[OFF_EBUF + (long)b*512 + te0 + tid] =
            U.e.ep[0][tid] + U.e.ep[1][tid] + U.e.ep[2][tid] + U.e.ep[3][tid];
    }
    gbar(bar, ++gen);

    // ========== phase S: softmax + ctx (block = b x d-slice128) ==========
    {
      const int b = B & 63, q4 = B >> 6;
      const float* eb = ws + OFF_EBUF + (long)b*512;
      float v = eb[tid];
      float m = v;
#pragma unroll
      for (int o = 32; o; o >>= 1) m = fmaxf(m, __shfl_xor(m, o));
      if ((tid & 63) == 0) U.s.wred[tid >> 6] = m;
      __syncthreads();
      float mx = U.s.wred[0];
#pragma unroll
      for (int i2 = 1; i2 < 8; ++i2) mx = fmaxf(mx, U.s.wred[i2]);
      float pe = __expf(v - mx);
      U.s.es[tid] = pe;
      float s = pe;
#pragma unroll
      for (int o = 32; o; o >>= 1) s += __shfl_xor(s, o);
      if ((tid & 63) == 0) U.s.wsum[tid >> 6] = s;
      __syncthreads();          // publishes es[] and wsum[]
      float tot = U.s.wsum[0];
#pragma unroll
      for (int i2 = 1; i2 < 8; ++i2) tot += U.s.wsum[i2];
      float inv = 1.f / tot;
      if (tid < 128)
        dout[DO_ATT + ((long)b*500 + t)*512 + q4*128 + tid] = U.s.es[q4*128 + tid] * inv;
      // ctx: thread = (dq 0..31 -> 4 d, th 0..15 -> 32 te)
      const int dq = tid & 31, th = tid >> 5;
      const float* ep = enc + (long)b*262144 + q4*128 + dq*4;
      float4 a4 = {0.f, 0.f, 0.f, 0.f};
#pragma unroll 8
      for (int te = th*32; te < th*32 + 32; ++te) {
        float sc = U.s.es[te];
        f4 ev = ld4v(&ep[(long)te*512]);   // cached: enc is L3-resident
        a4.x = fmaf(sc, ev.x, a4.x); a4.y = fmaf(sc, ev.y, a4.y);
        a4.z = fmaf(sc, ev.z, a4.z); a4.w = fmaf(sc, ev.w, a4.w);
      }
      *(float4*)&U.s.red[th][dq*4] = a4;
      __syncthreads();
      if (tid < 128) {
        float sm = 0.f;
#pragma unroll
        for (int th2 = 0; th2 < 16; ++th2) sm += U.s.red[th2][tid];
        ws[OFF_CTX + (long)b*512 + q4*128 + tid] = sm * inv;
      }
    }
    gbar(bar, ++gen);

    // ========== phases G0/G1: gate GEMM + LSTM cell ==========
    // Wave-independent pipeline: wave w owns batches w*8..w*8+7 with a private
    // LDS x-buffer. Lane = (row jr 0..15, k-quarter kq 0..3). Chunk = 64 k.
    // Depth-2 weight prefetch via even/odd register sets (no copies).
#pragma unroll 1
    for (int mode = 0; mode < 2; ++mode) {
      const int l = tid & 63, w = tid >> 6;
      const int jr = l & 15, kq = l >> 4;
      const int bs8 = w * 8;
      const long j = (long)(jr >> 2)*1024 + B*4 + (jr & 3);
      const int KH = mode ? 1024 : 768;
      const int LD = mode ? 1024 : 768;
      const int NC = mode ? 32 : 28;        // chunks of 64 k (even for both)
      const float* wih = mode ? wih1 : wih0;
      const float* whh = mode ? whh1 : whh0;
      const float* gbp = ws + (mode ? OFF_GB1 : OFF_GB0);
      const float* srcPre = ws + OFF_PRE + (long)t*64*256;
      const float* srcCtx = ws + OFF_CTX;
      const float* h0r = ws + OFF_H0A + (long)p*65536;
      const float* h0n = ws + OFF_H0A + (long)(1-p)*65536;
      const float* h1r = ws + OFF_H1A + (long)p*65536;
      float* xw = &U.g.xw[w][0][0];         // [8][64] row-major, this wave only

      const int bx0 = l >> 4, kx0 = (l & 15) * 4;

      auto xsrc = [&](int bx, int k) -> float4 {
        const int gb_ = bs8 + bx;
        if (mode == 0) {
          if (k < 256)  return ld4(srcPre + gb_*256 + k);
          if (k < 768)  return ld4(srcCtx + gb_*512 + (k - 256));
          return ld4(h0r + gb_*1024 + (k - 768));
        }
        return (k < 1024) ? ld4(h0n + gb_*1024 + k) : ld4(h1r + gb_*1024 + (k - 1024));
      };
      auto wload = [&](int c, f4& w0, f4& w1, f4& w2, f4& w3) {
        const int bk = c*64 + kq*16;
        const float* wp = (bk < KH) ? (wih + j*LD + bk) : (whh + j*1024 + (bk - KH));
        w0 = ld4v(wp); w1 = ld4v(wp + 4); w2 = ld4v(wp + 8); w3 = ld4v(wp + 12);
      };

      f4 wA0, wA1, wA2, wA3, wB0, wB1, wB2, wB3;
      float4 xA, xB;
      wload(0, wA0, wA1, wA2, wA3);
      wload(1, wB0, wB1, wB2, wB3);
      xA = xsrc(bx0, kx0);
      xB = xsrc(4 + bx0, kx0);

      float acc[8];
#pragma unroll
      for (int i = 0; i < 8; ++i) acc[i] = 0.f;

      auto chunk = [&](int c, f4& w0, f4& w1, f4& w2, f4& w3) {
        // stage chunk c (lane-linear -> conflict-free ds_write_b128)
        *(float4*)(xw + l*4)       = xA;
        *(float4*)(xw + 256 + l*4) = xB;
        if (c + 1 < NC) {   // x prefetch, depth 1 (L2-shared, short latency)
          xA = xsrc(bx0, (c+1)*64 + kx0);
          xB = xsrc(4 + bx0, (c+1)*64 + kx0);
        }
        asm volatile("s_waitcnt lgkmcnt(0)" ::: "memory");
        __builtin_amdgcn_sched_barrier(0);
#pragma unroll
        for (int i = 0; i < 8; ++i) {
          const float* xp = xw + i*64 + kq*16;
          float4 x0 = ld4(xp), x1 = ld4(xp + 4), x2 = ld4(xp + 8), x3 = ld4(xp + 12);
          acc[i] = dot4v(w3, x3, dot4v(w2, x2, dot4v(w1, x1, dot4v(w0, x0, acc[i]))));
        }
        __builtin_amdgcn_sched_barrier(0);
        if (c + 2 < NC)     // weight prefetch, depth 2 (reuses this set's regs)
          wload(c + 2, w0, w1, w2, w3);
      };

      for (int c = 0; c < NC; c += 2) {
        chunk(c,     wA0, wA1, wA2, wA3);
        chunk(c + 1, wB0, wB1, wB2, wB3);
      }

      // reduce k-quarters (lanes ^16, ^32 share jr)
#pragma unroll
      for (int i = 0; i < 8; ++i) {
        acc[i] += __shfl_xor(acc[i], 16);
        acc[i] += __shfl_xor(acc[i], 32);
      }
      if (kq == 0) {
        float bias = gbp[j];
#pragma unroll
        for (int i = 0; i < 8; ++i) U.g.gsh[jr][bs8 + i] = acc[i] + bias;
      }
      __syncthreads();
      if (tid < 256) {
        const int b2 = tid & 63, u4 = tid >> 6;
        float iv = U.g.gsh[u4][b2];
        float fv = U.g.gsh[4 + u4][b2];
        float gv = U.g.gsh[8 + u4][b2];
        float ov = U.g.gsh[12 + u4][b2];
        long hw = (mode ? OFF_H1A : OFF_H0A) + (long)(1-p)*65536 + (long)b2*1024 + B*4 + u4;
        long cw = (mode ? OFF_C1 : OFF_C0) + (long)b2*1024 + B*4 + u4;
        float cold = ws[cw];
        float c2 = fsigmoid(fv)*cold + fsigmoid(iv)*ftanh(gv);
        ws[cw] = c2;
        ws[hw] = fsigmoid(ov)*ftanh(c2);
      }
      gbar(bar, ++gen);
    }

    // ========== phase M: mel / stop / q (block = b x part) ==========
    {
      const int b = B & 63, part = B >> 6;
      const float* h1n = ws + OFF_H1A + (long)(1-p)*65536;
      const float* ctx = ws + OFF_CTX;
      for (int i = tid; i < 1536; i += NTHR)
        U.m.xs[i] = (i < 1024) ? h1n[b*1024 + i] : ctx[b*512 + (i - 1024)];
      __syncthreads();
      const int grp = tid >> 3, l8 = tid & 7;
      const int kb = l8 * 4;
      if (part == 0 || (part == 3 && grp < 16)) {
        const int jj = (part == 0) ? grp : 64 + grp;
        const float* wrp = mw + (long)jj*1536;
        float4 a4 = {0.f, 0.f, 0.f, 0.f};
#pragma unroll 8
        for (int i = 0; i < 48; ++i) {
          float4 xv = ld4(&U.m.xs[kb + i*32]);
          float4 wv = ld4(&wrp[kb + i*32]);
          a4.x = fmaf(xv.x, wv.x, a4.x); a4.y = fmaf(xv.y, wv.y, a4.y);
          a4.z = fmaf(xv.z, wv.z, a4.z); a4.w = fmaf(xv.w, wv.w, a4.w);
        }
        float acc = (a4.x + a4.y) + (a4.z + a4.w);
        acc += __shfl_xor(acc, 1);
        acc += __shfl_xor(acc, 2);
        acc += __shfl_xor(acc, 4);
        if (l8 == 0) dout[DO_MEL + ((long)b*500 + t)*80 + jj] = acc + mb[jj];
      } else if (part == 1 || part == 2) {
        const int a = (part - 1)*64 + grp;
        const float* wrp = aq + (long)a*1024;
        float4 a4 = {0.f, 0.f, 0.f, 0.f};
#pragma unroll 8
        for (int i = 0; i < 32; ++i) {
          float4 xv = ld4(&U.m.xs[kb + i*32]);
          float4 wv = ld4(&wrp[kb + i*32]);
          a4.x = fmaf(xv.x, wv.x, a4.x); a4.y = fmaf(xv.y, wv.y, a4.y);
          a4.z = fmaf(xv.z, wv.z, a4.z); a4.w = fmaf(xv.w, wv.w, a4.w);
        }
        float acc = (a4.x + a4.y) + (a4.z + a4.w);
        acc += __shfl_xor(acc, 1);
        acc += __shfl_xor(acc, 2);
        acc += __shfl_xor(acc, 4);
        if (l8 == 0) ws[OFF_Q + b*128 + a] = acc;
      } else if (part == 3 && grp == 16) {
        float4 a4 = {0.f, 0.f, 0.f, 0.f};
#pragma unroll 8
        for (int i = 0; i < 48; ++i) {
          float4 xv = ld4(&U.m.xs[kb + i*32]);
          float4 wv = ld4(&sw[kb + i*32]);
          a4.x = fmaf(xv.x, wv.x, a4.x); a4.y = fmaf(xv.y, wv.y, a4.y);
          a4.z = fmaf(xv.z, wv.z, a4.z); a4.w = fmaf(xv.w, wv.w, a4.w);
        }
        float acc = (a4.x + a4.y) + (a4.z + a4.w);
        acc += __shfl_xor(acc, 1);
        acc += __shfl_xor(acc, 2);
        acc += __shfl_xor(acc, 4);
        if (l8 == 0) dout[DO_STOP + (long)b*500 + t] = acc + sb[0];
      }
    }
    gbar(bar, ++gen);
  }
}

// ---------------- epilog: postnet conv layer ----------------
__global__ __launch_bounds__(256) void k_conv(
    const float* __restrict__ in, float* __restrict__ out,
    const float* __restrict__ wT, const float* __restrict__ pb,
    const float* __restrict__ bg, const float* __restrict__ bbp,
    const float* __restrict__ melp,
    int CI, int CO, int flags)
{
  int tx = blockIdx.x, cy = blockIdx.y, b = blockIdx.z;
  int tid = threadIdx.x;
  int tl = tid & 63;
  int cog = __builtin_amdgcn_readfirstlane((int)(tid >> 6));
  int t0 = tx * 64;
  int co0 = cy*64 + cog*16;
  __shared__ float xs[16][68];
  float acc[16];
#pragma unroll
  for (int i = 0; i < 16; ++i) acc[i] = 0.f;
  for (int ci0 = 0; ci0 < CI; ci0 += 16) {
    for (int i = tid; i < 16*68; i += 256) {
      int cl = i / 68, tt = i - cl*68;
      int tg = t0 + tt - 2;
      float v = 0.f;
      if (tg >= 0 && tg < 500) {
        if (flags & 1) v = in[((long)b*500 + tg)*80 + (ci0 + cl)];
        else           v = in[((long)b*CI + ci0 + cl)*500 + tg];
      }
      xs[cl][tt] = v;
    }
    __syncthreads();
    for (int cl = 0; cl < 16; ++cl) {
#pragma unroll
      for (int k = 0; k < 5; ++k) {
        const float* wr = wT + ((long)((ci0 + cl)*5 + k))*CO + co0;
        float xv = xs[cl][tl + k];
#pragma unroll
        for (int i = 0; i < 16; ++i) acc[i] = fmaf(xv, wr[i], acc[i]);
      }
    }
    __syncthreads();
  }
  int tg = t0 + tl;
  if (tg < 500) {
    const float RS = 0.99999500003749969f;
#pragma unroll
    for (int i = 0; i < 16; ++i) {
      int co = co0 + i;
      if (co < CO) {
        float sc = bg[co] * RS;
        float v = fmaf(acc[i], sc, fmaf(pb[co], sc, bbp[co]));
        if (flags & 4) v = ftanh(v);
        if (flags & 2) { long oi = ((long)b*500 + tg)*80 + co; out[oi] = melp[oi] + v; }
        else out[((long)b*CO + co)*500 + tg] = v;
      }
    }
  }
}

// ---------------- launch ----------------
extern "C" void kernel_launch(void* const* d_in, const int* in_sizes, int n_in,
                              void* d_out, int out_size, void* d_ws, size_t ws_size,
                              hipStream_t stream)
{
  (void)in_sizes; (void)n_in; (void)out_size; (void)ws_size;
  const float* enc     = (const float*)d_in[0];
  const float* mel_tgt = (const float*)d_in[1];
  const float* p1w = (const float*)d_in[2];
  const float* p1b = (const float*)d_in[3];
  const float* p2w = (const float*)d_in[4];
  const float* p2b = (const float*)d_in[5];
  const float* wih0 = (const float*)d_in[6];
  const float* whh0 = (const float*)d_in[7];
  const float* bih0 = (const float*)d_in[8];
  const float* bhh0 = (const float*)d_in[9];
  const float* wih1 = (const float*)d_in[10];
  const float* whh1 = (const float*)d_in[11];
  const float* bih1 = (const float*)d_in[12];
  const float* bhh1 = (const float*)d_in[13];
  const float* aq   = (const float*)d_in[14];
  const float* am   = (const float*)d_in[15];
  const float* al   = (const float*)d_in[16];
  const float* alcw = (const float*)d_in[17];
  const float* alcb = (const float*)d_in[18];
  const float* ae   = (const float*)d_in[19];
  const float* ab   = (const float*)d_in[20];
  const float* mw   = (const float*)d_in[21];
  const float* mb   = (const float*)d_in[22];
  const float* sw   = (const float*)d_in[23];
  const float* sb   = (const float*)d_in[24];
  const float* pw0 = (const float*)d_in[25];
  const float* pb0 = (const float*)d_in[26];
  const float* bg0 = (const float*)d_in[27];
  const float* bb0 = (const float*)d_in[28];
  const float* pw1 = (const float*)d_in[29];
  const float* pb1 = (const float*)d_in[30];
  const float* bg1 = (const float*)d_in[31];
  const float* bb1 = (const float*)d_in[32];
  const float* pw2 = (const float*)d_in[33];
  const float* pb2 = (const float*)d_in[34];
  const float* bg2 = (const float*)d_in[35];
  const float* bb2 = (const float*)d_in[36];
  const float* pw3 = (const float*)d_in[37];
  const float* pb3 = (const float*)d_in[38];
  const float* bg3 = (const float*)d_in[39];
  const float* bb3 = (const float*)d_in[40];
  const float* pw4 = (const float*)d_in[41];
  const float* pb4 = (const float*)d_in[42];
  const float* bg4 = (const float*)d_in[43];
  const float* bb4 = (const float*)d_in[44];

  float* ws = (float*)d_ws;
  float* dout = (float*)d_out;

  // prolog
  k_prep<<<dim3(2048), 256, 0, stream>>>(bih0, bhh0, bih1, bhh1, al, alcw, alcb, ab,
                                         am, p1w, p2w, mw, aq, pw0, pw1, pw2, pw3, pw4, ws);
  k_prenet<<<dim3(500), 256, 0, stream>>>(mel_tgt, p1b, p2b, ws);
  k_mem<<<dim3(2048), 256, 0, stream>>>(enc, ws);

  // fused persistent decode
  k_decode<<<dim3(NBLK), NTHR, 0, stream>>>(enc, ae, wih0, whh0, wih1, whh1,
                                            mw, mb, sw, sb, aq, dout, ws);

  // postnet
  k_conv<<<dim3(8, 8, 64), 256, 0, stream>>>(dout + DO_MEL, ws + OFF_PB0, ws + OFF_PWT0,
                                             pb0, bg0, bb0, nullptr, 80, 512, 1 | 4);
  k_conv<<<dim3(8, 8, 64), 256, 0, stream>>>(ws + OFF_PB0, ws + OFF_PB1, ws + OFF_PWT1,
                                             pb1, bg1, bb1, nullptr, 512, 512, 4);
  k_conv<<<dim3(8, 8, 64), 256, 0, stream>>>(ws + OFF_PB1, ws + OFF_PB0, ws + OFF_PWT2,
                                             pb2, bg2, bb2, nullptr, 512, 512, 4);
  k_conv<<<dim3(8, 8, 64), 256, 0, stream>>>(ws + OFF_PB0, ws + OFF_PB1, ws + OFF_PWT3,
                                             pb3, bg3, bb3, nullptr, 512, 512, 4);
  k_conv<<<dim3(8, 2, 64), 256, 0, stream>>>(ws + OFF_PB1, dout, ws + OFF_PWT4,
                                             pb4, bg4, bb4, dout + DO_MEL, 512, 80, 2);
}

// Round 5
// 95199.329 us; speedup vs baseline: 6.9661x; 6.9661x over previous
//
#include <hip/hip_runtime.h>
#include <math.h>

// ============================================================
// Tacotron2 decoder, fp32. Round 6: persistent decode, no-spill + cached streams.
// B=64, T_ENC=512, T_DEC=500, MEL=80, PRE=256, ENC_D=512, H=1024, ATT=128
//
// Round-5 finding: depth-2 prefetch restructure spilled VGPRs (cap 128) ->
// scratch traffic 2 TB (WRITE 1.26 TB), 6x regression. The cached-vs-nt
// question was never tested.
// Round-6: exact round-4 (112 ms) gate structure (depth-1, no spill) +
// cached loads for weights/enc/mem (L3 residency) + __launch_bounds__(512,2)
// so the allocator has 256 VGPRs (2 waves/SIMD = exactly our occupancy).
// ============================================================

// ---------------- ws layout (float offsets) ----------------
static constexpr long OFF_AMT  = 0;                       // amT[512][128]
static constexpr long OFF_P1WT = OFF_AMT  + 512L*128;     // p1wT[80][256]
static constexpr long OFF_P2WT = OFF_P1WT + 80L*256;      // p2wT[256][256]
static constexpr long OFF_MWT  = OFF_P2WT + 256L*256;     // mwT (unused by decode)
static constexpr long OFF_AQT  = OFF_MWT  + 1536L*80;     // aqT (unused by decode)
static constexpr long OFF_WLOC = OFF_AQT  + 1024L*128;    // W_loc[128][32] (legacy)
static constexpr long OFF_BLOC = OFF_WLOC + 128L*32;      // bloc[128] = al@alcb + ab
static constexpr long OFF_WLT  = OFF_BLOC + 128;          // WlT[32][128]
static constexpr long OFF_GB0  = OFF_WLT  + 4096;         // bih0+bhh0 [4096]
static constexpr long OFF_GB1  = OFF_GB0  + 4096;         // bih1+bhh1 [4096]
static constexpr long OFF_PWT0 = OFF_GB1  + 4096;         // postnet wT0 [400][512]
static constexpr long OFF_PWT1 = OFF_PWT0 + 400L*512;     // [2560][512]
static constexpr long OFF_PWT2 = OFF_PWT1 + 2560L*512;
static constexpr long OFF_PWT3 = OFF_PWT2 + 2560L*512;
static constexpr long OFF_PWT4 = OFF_PWT3 + 2560L*512;    // [2560][80]
static constexpr long OFF_PRE  = OFF_PWT4 + 2560L*80;     // pre_all[500*64][256]
static constexpr long OFF_MEM  = OFF_PRE  + 500L*64*256;  // mem[64][512][128]
static constexpr long OFF_H0A  = OFF_MEM  + 64L*512*128;  // -- zero region start --
static constexpr long OFF_H0B  = OFF_H0A  + 64L*1024;
static constexpr long OFF_H1A  = OFF_H0B  + 64L*1024;
static constexpr long OFF_H1B  = OFF_H1A  + 64L*1024;
static constexpr long OFF_C0   = OFF_H1B  + 64L*1024;
static constexpr long OFF_C1   = OFF_C0   + 64L*1024;
static constexpr long OFF_Q    = OFF_C1   + 64L*1024;     // q[64][128]
static constexpr long OFF_CTX  = OFF_Q    + 64L*128;      // ctx[64][512]
static constexpr long OFF_EBUF = OFF_CTX  + 64L*512;      // e[64][512]
static constexpr long OFF_PB0  = OFF_EBUF + 64L*512;      // postnet buf [64][512][500]
static constexpr long OFF_PB1  = OFF_PB0  + 64L*512*500;
static constexpr long WS_FLOATS = OFF_PB1 + 64L*512*500;  // ~201.5 MB

static constexpr long OFF_BAR = OFF_PB0;   // barrier flags (re-init by k_prep)

// d_out layout: [mel+post | mel | stop | attw]
static constexpr long DO_MEL  = 64L*500*80;
static constexpr long DO_STOP = 2*DO_MEL;
static constexpr long DO_ATT  = DO_STOP + 64L*500;

static constexpr long ZERO_CNT = OFF_EBUF - OFF_H0A;
static constexpr long PREP_TOTAL = ZERO_CNT + 4096 + 4096 + 4096 + 128 + 4096
  + 65536 + 20480 + 65536 + 122880 + 131072
  + 204800 + 1310720 + 1310720 + 1310720 + 204800;

static constexpr int NBLK = 256;
static constexpr int NTHR = 512;

typedef float f4 __attribute__((ext_vector_type(4)));

__device__ __forceinline__ float fsigmoid(float x) { return 1.f / (1.f + __expf(-x)); }
__device__ __forceinline__ float ftanh(float x) {
  float ax = fminf(fabsf(x), 15.f);
  float e = __expf(-2.f * ax);
  float r = (1.f - e) / (1.f + e);
  return copysignf(r, x);
}
__device__ __forceinline__ float4 ld4(const float* p) { return *(const float4*)p; }
__device__ __forceinline__ f4 ld4v(const float* p) { return *(const f4*)p; }
__device__ __forceinline__ float dot4(float4 w, float4 x, float acc) {
  acc = fmaf(w.x, x.x, acc); acc = fmaf(w.y, x.y, acc);
  acc = fmaf(w.z, x.z, acc); acc = fmaf(w.w, x.w, acc);
  return acc;
}
__device__ __forceinline__ float dot4v(f4 w, float4 x, float acc) {
  acc = fmaf(w.x, x.x, acc); acc = fmaf(w.y, x.y, acc);
  acc = fmaf(w.z, x.z, acc); acc = fmaf(w.w, x.w, acc);
  return acc;
}

// ---------------- parallel flag-tree grid barrier ----------------
__device__ __forceinline__ void gbar(unsigned* bar, unsigned gen) {
  __syncthreads();
  if (blockIdx.x == 0) {
    if (threadIdx.x > 0 && threadIdx.x < 256) {
      while (__hip_atomic_load(&bar[threadIdx.x*16], __ATOMIC_RELAXED,
                               __HIP_MEMORY_SCOPE_AGENT) != gen)
        __builtin_amdgcn_s_sleep(1);
    }
    __syncthreads();
    if (threadIdx.x == 0)
      __hip_atomic_store(&bar[4096], gen, __ATOMIC_RELEASE, __HIP_MEMORY_SCOPE_AGENT);
  } else {
    if (threadIdx.x == 0) {
      __hip_atomic_store(&bar[blockIdx.x*16], gen, __ATOMIC_RELEASE,
                         __HIP_MEMORY_SCOPE_AGENT);
      while (__hip_atomic_load(&bar[4096], __ATOMIC_RELAXED,
                               __HIP_MEMORY_SCOPE_AGENT) != gen)
        __builtin_amdgcn_s_sleep(1);
    }
  }
  if (threadIdx.x == 0) __threadfence();
  __syncthreads();
}

// ---------------- prolog: transposes / fused constants / zero-init ----------------
__global__ __launch_bounds__(256) void k_prep(
    const float* __restrict__ bih0, const float* __restrict__ bhh0,
    const float* __restrict__ bih1, const float* __restrict__ bhh1,
    const float* __restrict__ al,   const float* __restrict__ alcw,
    const float* __restrict__ alcb, const float* __restrict__ ab,
    const float* __restrict__ am,   const float* __restrict__ p1w,
    const float* __restrict__ p2w,  const float* __restrict__ mw,
    const float* __restrict__ aq,
    const float* __restrict__ pw0, const float* __restrict__ pw1,
    const float* __restrict__ pw2, const float* __restrict__ pw3,
    const float* __restrict__ pw4,
    float* __restrict__ ws)
{
  if (blockIdx.x == 0) {
    unsigned* bar = (unsigned*)(ws + OFF_BAR);
    for (int i = threadIdx.x; i < 4160; i += 256) bar[i] = 0u;
  }
  long stride = (long)gridDim.x * 256;
  for (long idx = (long)blockIdx.x * 256 + threadIdx.x; idx < PREP_TOTAL; idx += stride) {
    long r = idx;
    if (r < ZERO_CNT) { ws[OFF_H0A + r] = 0.f; continue; }
    r -= ZERO_CNT;
    if (r < 4096) { ws[OFF_GB0 + r] = bih0[r] + bhh0[r]; continue; }
    r -= 4096;
    if (r < 4096) { ws[OFF_GB1 + r] = bih1[r] + bhh1[r]; continue; }
    r -= 4096;
    if (r < 4096) {
      int a = (int)(r >> 5), k = (int)(r & 31);
      float v = 0.f;
      if (k < 31) for (int ch = 0; ch < 32; ++ch) v += al[a*32 + ch] * alcw[ch*31 + k];
      ws[OFF_WLOC + r] = v; continue;
    }
    r -= 4096;
    if (r < 128) {
      float v = ab[r];
      for (int ch = 0; ch < 32; ++ch) v += al[r*32 + ch] * alcb[ch];
      ws[OFF_BLOC + r] = v; continue;
    }
    r -= 128;
    if (r < 4096) {   // WlT[k][a]
      int k = (int)(r >> 7), a = (int)(r & 127);
      float v = 0.f;
      if (k < 31) for (int ch = 0; ch < 32; ++ch) v += al[a*32 + ch] * alcw[ch*31 + k];
      ws[OFF_WLT + r] = v; continue;
    }
    r -= 4096;
    if (r < 65536) { int d = (int)(r >> 7), a2 = (int)(r & 127); ws[OFF_AMT + r] = am[(long)a2*512 + d]; continue; }
    r -= 65536;
    if (r < 20480) { int k = (int)(r >> 8), j = (int)(r & 255); ws[OFF_P1WT + r] = p1w[j*80 + k]; continue; }
    r -= 20480;
    if (r < 65536) { int k = (int)(r >> 8), j = (int)(r & 255); ws[OFF_P2WT + r] = p2w[j*256 + k]; continue; }
    r -= 65536;
    if (r < 122880) { int k = (int)(r / 80), c = (int)(r % 80); ws[OFF_MWT + r] = mw[(long)c*1536 + k]; continue; }
    r -= 122880;
    if (r < 131072) { int k = (int)(r >> 7), a2 = (int)(r & 127); ws[OFF_AQT + r] = aq[(long)a2*1024 + k]; continue; }
    r -= 131072;
    if (r < 204800) { int c5 = (int)(r / 512), co = (int)(r % 512); ws[OFF_PWT0 + r] = pw0[((long)co*80  + c5/5)*5 + (c5%5)]; continue; }
    r -= 204800;
    if (r < 1310720) { int c5 = (int)(r / 512), co = (int)(r % 512); ws[OFF_PWT1 + r] = pw1[((long)co*512 + c5/5)*5 + (c5%5)]; continue; }
    r -= 1310720;
    if (r < 1310720) { int c5 = (int)(r / 512), co = (int)(r % 512); ws[OFF_PWT2 + r] = pw2[((long)co*512 + c5/5)*5 + (c5%5)]; continue; }
    r -= 1310720;
    if (r < 1310720) { int c5 = (int)(r / 512), co = (int)(r % 512); ws[OFF_PWT3 + r] = pw3[((long)co*512 + c5/5)*5 + (c5%5)]; continue; }
    r -= 1310720;
    { int c5 = (int)(r / 80), co = (int)(r % 80); ws[OFF_PWT4 + r] = pw4[((long)co*512 + c5/5)*5 + (c5%5)]; }
  }
}

// ---------------- prolog: prenet for all 500 steps ----------------
__global__ __launch_bounds__(256) void k_prenet(
    const float* __restrict__ mel_tgt, const float* __restrict__ p1b,
    const float* __restrict__ p2b, float* __restrict__ ws)
{
  int t = blockIdx.x, tid = threadIdx.x;
  const float* p1wT = ws + OFF_P1WT;
  const float* p2wT = ws + OFF_P2WT;
  __shared__ float prev_s[16][80];
  __shared__ float h1_s[16][256];
  for (int sb = 0; sb < 4; ++sb) {
    int b0 = sb * 16;
    for (int i = tid; i < 16*80; i += 256) {
      int rr = i / 80, k = i - rr*80;
      float v = 0.f;
      if (t > 0) v = mel_tgt[((long)(b0 + rr)*500 + (t-1))*80 + k];
      prev_s[rr][k] = v;
    }
    __syncthreads();
    int j = tid;
    for (int rr = 0; rr < 16; ++rr) {
      float acc = p1b[j];
      for (int k = 0; k < 80; ++k) acc = fmaf(prev_s[rr][k], p1wT[k*256 + j], acc);
      h1_s[rr][j] = fmaxf(acc, 0.f);
    }
    __syncthreads();
    for (int rr = 0; rr < 16; ++rr) {
      float acc = p2b[j];
      for (int k = 0; k < 256; ++k) acc = fmaf(h1_s[rr][k], p2wT[k*256 + j], acc);
      ws[OFF_PRE + ((long)t*64 + b0 + rr)*256 + j] = fmaxf(acc, 0.f);
    }
    __syncthreads();
  }
}

// ---------------- prolog: mem = enc @ am.T ----------------
__global__ __launch_bounds__(256) void k_mem(const float* __restrict__ enc, float* __restrict__ ws)
{
  int row0 = blockIdx.x * 16;
  int tid = threadIdx.x;
  int a = tid & 127, rh = tid >> 7;
  const float* amT = ws + OFF_AMT;
  __shared__ float encS[16][65];
  float acc[8];
#pragma unroll
  for (int i = 0; i < 8; ++i) acc[i] = 0.f;
  for (int k0 = 0; k0 < 512; k0 += 64) {
    for (int i = tid; i < 16*64; i += 256) {
      int rr = i >> 6, kk = i & 63;
      encS[rr][kk] = enc[(long)(row0 + rr)*512 + k0 + kk];
    }
    __syncthreads();
    for (int kk = 0; kk < 64; ++kk) {
      float w = amT[(long)(k0 + kk)*128 + a];
#pragma unroll
      for (int rr = 0; rr < 8; ++rr) acc[rr] = fmaf(encS[rh*8 + rr][kk], w, acc[rr]);
    }
    __syncthreads();
  }
#pragma unroll
  for (int rr = 0; rr < 8; ++rr)
    ws[OFF_MEM + (long)(row0 + rh*8 + rr)*128 + a] = acc[rr];
}

// ---------------- persistent fused decode kernel ----------------
struct SmemE { float ap[160]; float bq[128]; float ep[4][132]; };
struct SmemS { float es[512]; float wred[8]; float wsum[8]; float red[16][132]; };
struct SmemG { float xw[8][8][64]; float gsh[16][65]; };   // per-wave x buffers
struct SmemM { float xs[1536]; };
union SmemU { SmemE e; SmemS s; SmemG g; SmemM m; };

__global__ __launch_bounds__(NTHR, 2) void k_decode(
    const float* __restrict__ enc, const float* __restrict__ ae,
    const float* __restrict__ wih0, const float* __restrict__ whh0,
    const float* __restrict__ wih1, const float* __restrict__ whh1,
    const float* __restrict__ mw, const float* __restrict__ mb,
    const float* __restrict__ sw, const float* __restrict__ sb,
    const float* __restrict__ aq,
    float* __restrict__ dout, float* __restrict__ ws)
{
  const int B = blockIdx.x;
  const int tid = threadIdx.x;
  unsigned* bar = (unsigned*)(ws + OFF_BAR);
  unsigned gen = 0;

  __shared__ float WlTs[4096];
  __shared__ float aeS[128];
  __shared__ SmemU U;

  for (int i = tid; i < 4096; i += NTHR) WlTs[i] = ws[OFF_WLT + i];
  if (tid < 128) aeS[tid] = ae[tid];
  __syncthreads();

  for (int t = 0; t < 500; ++t) {
    const int p = t & 1;

    // ========== phase E: attention energies (block = b x te-chunk128) ==========
    {
      const int b = B & 63, cc2 = B >> 6;
      const int te0 = cc2 * 128;
      const int tel = tid & 127, ag = tid >> 7;
      const int a0 = ag * 32;
      for (int i = tid; i < 158; i += NTHR) {
        int gte = te0 + i - 15;
        float v = 0.f;
        if (t > 0 && gte >= 0 && gte < 512)
          v = dout[DO_ATT + ((long)b*500 + (t-1))*512 + gte];
        U.e.ap[i] = v;
      }
      if (tid < 128) U.e.bq[tid] = ws[OFF_Q + b*128 + tid] + ws[OFF_BLOC + tid];
      __syncthreads();
      float acc[32];
#pragma unroll
      for (int i = 0; i < 32; ++i) acc[i] = 0.f;
      for (int k = 0; k < 31; ++k) {
        float apk = U.e.ap[tel + k];
#pragma unroll
        for (int a4 = 0; a4 < 8; ++a4) {
          float4 wv = ld4(&WlTs[k*128 + a0 + a4*4]);
          acc[a4*4+0] = fmaf(apk, wv.x, acc[a4*4+0]);
          acc[a4*4+1] = fmaf(apk, wv.y, acc[a4*4+1]);
          acc[a4*4+2] = fmaf(apk, wv.z, acc[a4*4+2]);
          acc[a4*4+3] = fmaf(apk, wv.w, acc[a4*4+3]);
        }
      }
      const float* memp = ws + OFF_MEM + ((long)b*512 + te0 + tel)*128 + a0;
      float esum = 0.f;
#pragma unroll
      for (int a4 = 0; a4 < 8; ++a4) {
        f4 mv = ld4v(&memp[a4*4]);      // cached: mem should be L3-resident
        float4 bq = ld4(&U.e.bq[a0 + a4*4]);
        float4 av = ld4(&aeS[a0 + a4*4]);
        esum = fmaf(av.x, ftanh(acc[a4*4+0] + bq.x + mv.x), esum);
        esum = fmaf(av.y, ftanh(acc[a4*4+1] + bq.y + mv.y), esum);
        esum = fmaf(av.z, ftanh(acc[a4*4+2] + bq.z + mv.z), esum);
        esum = fmaf(av.w, ftanh(acc[a4*4+3] + bq.w + mv.w), esum);
      }
      U.e.ep[ag][tel] = esum;
      __syncthreads();
      if (tid < 128)
        ws[OFF_EBUF + (long)b*512 + te0 + tid] =
            U.e.ep[0][tid] + U.e.ep[1][tid] + U.e.ep[2][tid] + U.e.ep[3][tid];
    }
    gbar(bar, ++gen);

    // ========== phase S: softmax + ctx (block = b x d-slice128) ==========
    {
      const int b = B & 63, q4 = B >> 6;
      const float* eb = ws + OFF_EBUF + (long)b*512;
      float v = eb[tid];
      float m = v;
#pragma unroll
      for (int o = 32; o; o >>= 1) m = fmaxf(m, __shfl_xor(m, o));
      if ((tid & 63) == 0) U.s.wred[tid >> 6] = m;
      __syncthreads();
      float mx = U.s.wred[0];
#pragma unroll
      for (int i2 = 1; i2 < 8; ++i2) mx = fmaxf(mx, U.s.wred[i2]);
      float pe = __expf(v - mx);
      U.s.es[tid] = pe;
      float s = pe;
#pragma unroll
      for (int o = 32; o; o >>= 1) s += __shfl_xor(s, o);
      if ((tid & 63) == 0) U.s.wsum[tid >> 6] = s;
      __syncthreads();          // publishes es[] and wsum[]
      float tot = U.s.wsum[0];
#pragma unroll
      for (int i2 = 1; i2 < 8; ++i2) tot += U.s.wsum[i2];
      float inv = 1.f / tot;
      if (tid < 128)
        dout[DO_ATT + ((long)b*500 + t)*512 + q4*128 + tid] = U.s.es[q4*128 + tid] * inv;
      // ctx: thread = (dq 0..31 -> 4 d, th 0..15 -> 32 te)
      const int dq = tid & 31, th = tid >> 5;
      const float* ep = enc + (long)b*262144 + q4*128 + dq*4;
      float4 a4 = {0.f, 0.f, 0.f, 0.f};
#pragma unroll 8
      for (int te = th*32; te < th*32 + 32; ++te) {
        float sc = U.s.es[te];
        f4 ev = ld4v(&ep[(long)te*512]);   // cached: enc should be L3-resident
        a4.x = fmaf(sc, ev.x, a4.x); a4.y = fmaf(sc, ev.y, a4.y);
        a4.z = fmaf(sc, ev.z, a4.z); a4.w = fmaf(sc, ev.w, a4.w);
      }
      *(float4*)&U.s.red[th][dq*4] = a4;
      __syncthreads();
      if (tid < 128) {
        float sm = 0.f;
#pragma unroll
        for (int th2 = 0; th2 < 16; ++th2) sm += U.s.red[th2][tid];
        ws[OFF_CTX + (long)b*512 + q4*128 + tid] = sm * inv;
      }
    }
    gbar(bar, ++gen);

    // ========== phases G0/G1: gate GEMM + LSTM cell ==========
    // Wave-independent pipeline (round-4 structure, 124 VGPR, no spill):
    // wave w owns batches w*8..w*8+7, private LDS x-buffer, lane = (jr, kq),
    // chunk = 64 k, depth-1 register prefetch of W + x.
#pragma unroll 1
    for (int mode = 0; mode < 2; ++mode) {
      const int l = tid & 63, w = tid >> 6;
      const int jr = l & 15, kq = l >> 4;
      const int bs8 = w * 8;
      const long j = (long)(jr >> 2)*1024 + B*4 + (jr & 3);
      const int KH = mode ? 1024 : 768;
      const int LD = mode ? 1024 : 768;
      const int NC = mode ? 32 : 28;        // chunks of 64 k
      const float* wih = mode ? wih1 : wih0;
      const float* whh = mode ? whh1 : whh0;
      const float* gbp = ws + (mode ? OFF_GB1 : OFF_GB0);
      const float* srcPre = ws + OFF_PRE + (long)t*64*256;
      const float* srcCtx = ws + OFF_CTX;
      const float* h0r = ws + OFF_H0A + (long)p*65536;
      const float* h0n = ws + OFF_H0A + (long)(1-p)*65536;
      const float* h1r = ws + OFF_H1A + (long)p*65536;
      float* xw = &U.g.xw[w][0][0];         // [8][64] row-major, this wave only

      const int bx0 = l >> 4, kx0 = (l & 15) * 4;

      auto xsrc = [&](int bx, int k) -> float4 {
        const int gb_ = bs8 + bx;
        if (mode == 0) {
          if (k < 256)  return ld4(srcPre + gb_*256 + k);
          if (k < 768)  return ld4(srcCtx + gb_*512 + (k - 256));
          return ld4(h0r + gb_*1024 + (k - 768));
        }
        return (k < 1024) ? ld4(h0n + gb_*1024 + k) : ld4(h1r + gb_*1024 + (k - 1024));
      };

      f4 wr0, wr1, wr2, wr3, wn0, wn1, wn2, wn3;
      float4 xA, xB;
      {
        const int bk = kq * 16;
        const float* wp = (bk < KH) ? (wih + j*LD + bk) : (whh + j*1024 + (bk - KH));
        wr0 = ld4v(wp); wr1 = ld4v(wp + 4); wr2 = ld4v(wp + 8); wr3 = ld4v(wp + 12);
        xA = xsrc(bx0, kx0);
        xB = xsrc(4 + bx0, kx0);
      }
      float acc[8];
#pragma unroll
      for (int i = 0; i < 8; ++i) acc[i] = 0.f;

      for (int c = 0; c < NC; ++c) {
        // stage chunk c (lane-linear -> conflict-free ds_write_b128)
        *(float4*)(xw + l*4)       = xA;
        *(float4*)(xw + 256 + l*4) = xB;
        if (c + 1 < NC) {   // prefetch chunk c+1 (depth 1)
          const int bk = (c+1)*64 + kq*16;
          const float* wp = (bk < KH) ? (wih + j*LD + bk) : (whh + j*1024 + (bk - KH));
          wn0 = ld4v(wp); wn1 = ld4v(wp + 4); wn2 = ld4v(wp + 8); wn3 = ld4v(wp + 12);
          xA = xsrc(bx0, (c+1)*64 + kx0);
          xB = xsrc(4 + bx0, (c+1)*64 + kx0);
        }
        asm volatile("s_waitcnt lgkmcnt(0)" ::: "memory");
        __builtin_amdgcn_sched_barrier(0);
#pragma unroll
        for (int i = 0; i < 8; ++i) {
          const float* xp = xw + i*64 + kq*16;
          float4 x0 = ld4(xp), x1 = ld4(xp + 4), x2 = ld4(xp + 8), x3 = ld4(xp + 12);
          acc[i] = dot4v(wr3, x3, dot4v(wr2, x2, dot4v(wr1, x1, dot4v(wr0, x0, acc[i]))));
        }
        __builtin_amdgcn_sched_barrier(0);
        wr0 = wn0; wr1 = wn1; wr2 = wn2; wr3 = wn3;
      }

      // reduce k-quarters (lanes ^16, ^32 share jr)
#pragma unroll
      for (int i = 0; i < 8; ++i) {
        acc[i] += __shfl_xor(acc[i], 16);
        acc[i] += __shfl_xor(acc[i], 32);
      }
      if (kq == 0) {
        float bias = gbp[j];
#pragma unroll
        for (int i = 0; i < 8; ++i) U.g.gsh[jr][bs8 + i] = acc[i] + bias;
      }
      __syncthreads();
      if (tid < 256) {
        const int b2 = tid & 63, u4 = tid >> 6;
        float iv = U.g.gsh[u4][b2];
        float fv = U.g.gsh[4 + u4][b2];
        float gv = U.g.gsh[8 + u4][b2];
        float ov = U.g.gsh[12 + u4][b2];
        long hw = (mode ? OFF_H1A : OFF_H0A) + (long)(1-p)*65536 + (long)b2*1024 + B*4 + u4;
        long cw = (mode ? OFF_C1 : OFF_C0) + (long)b2*1024 + B*4 + u4;
        float cold = ws[cw];
        float c2 = fsigmoid(fv)*cold + fsigmoid(iv)*ftanh(gv);
        ws[cw] = c2;
        ws[hw] = fsigmoid(ov)*ftanh(c2);
      }
      gbar(bar, ++gen);
    }

    // ========== phase M: mel / stop / q (block = b x part) ==========
    {
      const int b = B & 63, part = B >> 6;
      const float* h1n = ws + OFF_H1A + (long)(1-p)*65536;
      const float* ctx = ws + OFF_CTX;
      for (int i = tid; i < 1536; i += NTHR)
        U.m.xs[i] = (i < 1024) ? h1n[b*1024 + i] : ctx[b*512 + (i - 1024)];
      __syncthreads();
      const int grp = tid >> 3, l8 = tid & 7;
      const int kb = l8 * 4;
      if (part == 0 || (part == 3 && grp < 16)) {
        const int jj = (part == 0) ? grp : 64 + grp;
        const float* wrp = mw + (long)jj*1536;
        float4 a4 = {0.f, 0.f, 0.f, 0.f};
#pragma unroll 8
        for (int i = 0; i < 48; ++i) {
          float4 xv = ld4(&U.m.xs[kb + i*32]);
          float4 wv = ld4(&wrp[kb + i*32]);
          a4.x = fmaf(xv.x, wv.x, a4.x); a4.y = fmaf(xv.y, wv.y, a4.y);
          a4.z = fmaf(xv.z, wv.z, a4.z); a4.w = fmaf(xv.w, wv.w, a4.w);
        }
        float acc = (a4.x + a4.y) + (a4.z + a4.w);
        acc += __shfl_xor(acc, 1);
        acc += __shfl_xor(acc, 2);
        acc += __shfl_xor(acc, 4);
        if (l8 == 0) dout[DO_MEL + ((long)b*500 + t)*80 + jj] = acc + mb[jj];
      } else if (part == 1 || part == 2) {
        const int a = (part - 1)*64 + grp;
        const float* wrp = aq + (long)a*1024;
        float4 a4 = {0.f, 0.f, 0.f, 0.f};
#pragma unroll 8
        for (int i = 0; i < 32; ++i) {
          float4 xv = ld4(&U.m.xs[kb + i*32]);
          float4 wv = ld4(&wrp[kb + i*32]);
          a4.x = fmaf(xv.x, wv.x, a4.x); a4.y = fmaf(xv.y, wv.y, a4.y);
          a4.z = fmaf(xv.z, wv.z, a4.z); a4.w = fmaf(xv.w, wv.w, a4.w);
        }
        float acc = (a4.x + a4.y) + (a4.z + a4.w);
        acc += __shfl_xor(acc, 1);
        acc += __shfl_xor(acc, 2);
        acc += __shfl_xor(acc, 4);
        if (l8 == 0) ws[OFF_Q + b*128 + a] = acc;
      } else if (part == 3 && grp == 16) {
        float4 a4 = {0.f, 0.f, 0.f, 0.f};
#pragma unroll 8
        for (int i = 0; i < 48; ++i) {
          float4 xv = ld4(&U.m.xs[kb + i*32]);
          float4 wv = ld4(&sw[kb + i*32]);
          a4.x = fmaf(xv.x, wv.x, a4.x); a4.y = fmaf(xv.y, wv.y, a4.y);
          a4.z = fmaf(xv.z, wv.z, a4.z); a4.w = fmaf(xv.w, wv.w, a4.w);
        }
        float acc = (a4.x + a4.y) + (a4.z + a4.w);
        acc += __shfl_xor(acc, 1);
        acc += __shfl_xor(acc, 2);
        acc += __shfl_xor(acc, 4);
        if (l8 == 0) dout[DO_STOP + (long)b*500 + t] = acc + sb[0];
      }
    }
    gbar(bar, ++gen);
  }
}

// ---------------- epilog: postnet conv layer ----------------
__global__ __launch_bounds__(256) void k_conv(
    const float* __restrict__ in, float* __restrict__ out,
    const float* __restrict__ wT, const float* __restrict__ pb,
    const float* __restrict__ bg, const float* __restrict__ bbp,
    const float* __restrict__ melp,
    int CI, int CO, int flags)
{
  int tx = blockIdx.x, cy = blockIdx.y, b = blockIdx.z;
  int tid = threadIdx.x;
  int tl = tid & 63;
  int cog = __builtin_amdgcn_readfirstlane((int)(tid >> 6));
  int t0 = tx * 64;
  int co0 = cy*64 + cog*16;
  __shared__ float xs[16][68];
  float acc[16];
#pragma unroll
  for (int i = 0; i < 16; ++i) acc[i] = 0.f;
  for (int ci0 = 0; ci0 < CI; ci0 += 16) {
    for (int i = tid; i < 16*68; i += 256) {
      int cl = i / 68, tt = i - cl*68;
      int tg = t0 + tt - 2;
      float v = 0.f;
      if (tg >= 0 && tg < 500) {
        if (flags & 1) v = in[((long)b*500 + tg)*80 + (ci0 + cl)];
        else           v = in[((long)b*CI + ci0 + cl)*500 + tg];
      }
      xs[cl][tt] = v;
    }
    __syncthreads();
    for (int cl = 0; cl < 16; ++cl) {
#pragma unroll
      for (int k = 0; k < 5; ++k) {
        const float* wr = wT + ((long)((ci0 + cl)*5 + k))*CO + co0;
        float xv = xs[cl][tl + k];
#pragma unroll
        for (int i = 0; i < 16; ++i) acc[i] = fmaf(xv, wr[i], acc[i]);
      }
    }
    __syncthreads();
  }
  int tg = t0 + tl;
  if (tg < 500) {
    const float RS = 0.99999500003749969f;
#pragma unroll
    for (int i = 0; i < 16; ++i) {
      int co = co0 + i;
      if (co < CO) {
        float sc = bg[co] * RS;
        float v = fmaf(acc[i], sc, fmaf(pb[co], sc, bbp[co]));
        if (flags & 4) v = ftanh(v);
        if (flags & 2) { long oi = ((long)b*500 + tg)*80 + co; out[oi] = melp[oi] + v; }
        else out[((long)b*CO + co)*500 + tg] = v;
      }
    }
  }
}

// ---------------- launch ----------------
extern "C" void kernel_launch(void* const* d_in, const int* in_sizes, int n_in,
                              void* d_out, int out_size, void* d_ws, size_t ws_size,
                              hipStream_t stream)
{
  (void)in_sizes; (void)n_in; (void)out_size; (void)ws_size;
  const float* enc     = (const float*)d_in[0];
  const float* mel_tgt = (const float*)d_in[1];
  const float* p1w = (const float*)d_in[2];
  const float* p1b = (const float*)d_in[3];
  const float* p2w = (const float*)d_in[4];
  const float* p2b = (const float*)d_in[5];
  const float* wih0 = (const float*)d_in[6];
  const float* whh0 = (const float*)d_in[7];
  const float* bih0 = (const float*)d_in[8];
  const float* bhh0 = (const float*)d_in[9];
  const float* wih1 = (const float*)d_in[10];
  const float* whh1 = (const float*)d_in[11];
  const float* bih1 = (const float*)d_in[12];
  const float* bhh1 = (const float*)d_in[13];
  const float* aq   = (const float*)d_in[14];
  const float* am   = (const float*)d_in[15];
  const float* al   = (const float*)d_in[16];
  const float* alcw = (const float*)d_in[17];
  const float* alcb = (const float*)d_in[18];
  const float* ae   = (const float*)d_in[19];
  const float* ab   = (const float*)d_in[20];
  const float* mw   = (const float*)d_in[21];
  const float* mb   = (const float*)d_in[22];
  const float* sw   = (const float*)d_in[23];
  const float* sb   = (const float*)d_in[24];
  const float* pw0 = (const float*)d_in[25];
  const float* pb0 = (const float*)d_in[26];
  const float* bg0 = (const float*)d_in[27];
  const float* bb0 = (const float*)d_in[28];
  const float* pw1 = (const float*)d_in[29];
  const float* pb1 = (const float*)d_in[30];
  const float* bg1 = (const float*)d_in[31];
  const float* bb1 = (const float*)d_in[32];
  const float* pw2 = (const float*)d_in[33];
  const float* pb2 = (const float*)d_in[34];
  const float* bg2 = (const float*)d_in[35];
  const float* bb2 = (const float*)d_in[36];
  const float* pw3 = (const float*)d_in[37];
  const float* pb3 = (const float*)d_in[38];
  const float* bg3 = (const float*)d_in[39];
  const float* bb3 = (const float*)d_in[40];
  const float* pw4 = (const float*)d_in[41];
  const float* pb4 = (const float*)d_in[42];
  const float* bg4 = (const float*)d_in[43];
  const float* bb4 = (const float*)d_in[44];

  float* ws = (float*)d_ws;
  float* dout = (float*)d_out;

  // prolog
  k_prep<<<dim3(2048), 256, 0, stream>>>(bih0, bhh0, bih1, bhh1, al, alcw, alcb, ab,
                                         am, p1w, p2w, mw, aq, pw0, pw1, pw2, pw3, pw4, ws);
  k_prenet<<<dim3(500), 256, 0, stream>>>(mel_tgt, p1b, p2b, ws);
  k_mem<<<dim3(2048), 256, 0, stream>>>(enc, ws);

  // fused persistent decode
  k_decode<<<dim3(NBLK), NTHR, 0, stream>>>(enc, ae, wih0, whh0, wih1, whh1,
                                            mw, mb, sw, sb, aq, dout, ws);

  // postnet
  k_conv<<<dim3(8, 8, 64), 256, 0, stream>>>(dout + DO_MEL, ws + OFF_PB0, ws + OFF_PWT0,
                                             pb0, bg0, bb0, nullptr, 80, 512, 1 | 4);
  k_conv<<<dim3(8, 8, 64), 256, 0, stream>>>(ws + OFF_PB0, ws + OFF_PB1, ws + OFF_PWT1,
                                             pb1, bg1, bb1, nullptr, 512, 512, 4);
  k_conv<<<dim3(8, 8, 64), 256, 0, stream>>>(ws + OFF_PB1, ws + OFF_PB0, ws + OFF_PWT2,
                                             pb2, bg2, bb2, nullptr, 512, 512, 4);
  k_conv<<<dim3(8, 8, 64), 256, 0, stream>>>(ws + OFF_PB0, ws + OFF_PB1, ws + OFF_PWT3,
                                             pb3, bg3, bb3, nullptr, 512, 512, 4);
  k_conv<<<dim3(8, 2, 64), 256, 0, stream>>>(ws + OFF_PB1, dout, ws + OFF_PWT4,
                                             pb4, bg4, bb4, dout + DO_MEL, 512, 80, 2);
}